// Round 1
// baseline (1554.393 us; speedup 1.0000x reference)
//
#include <hip/hip_runtime.h>
#include <hip/hip_bf16.h>

#define HDIM 1024
#define NTOK 2048
#define NHEAD 16
#define DHEAD 64
#define SEQ 1024
#define NEXP 8
#define FDIM 4096
#define LN_EPS 1e-5f

using f4    = __attribute__((ext_vector_type(4))) float;
using frag8 = __attribute__((ext_vector_type(8))) short;
using v4f   = __attribute__((ext_vector_type(4))) float;
typedef unsigned short ushortT;

__device__ __forceinline__ unsigned short f2bf(float x) {
  unsigned int u = __float_as_uint(x);
  unsigned int r = (u + 0x7fffu + ((u >> 16) & 1u)) >> 16;
  return (unsigned short)r;
}

// ---------------- zero control block ----------------
__global__ void k_zero(int* ctrl) {
  if (threadIdx.x < 32) ctrl[threadIdx.x] = 0;
}

// ---------------- LayerNorm (fp32 in -> fp32 out) ----------------
__global__ __launch_bounds__(256) void k_ln(
    const float* __restrict__ x, const float* __restrict__ g,
    const float* __restrict__ b, float* __restrict__ out) {
  int row = blockIdx.x, t = threadIdx.x;
  f4 v = ((const f4*)(x + (size_t)row * HDIM))[t];
  float s  = v[0] + v[1] + v[2] + v[3];
  float ss = v[0]*v[0] + v[1]*v[1] + v[2]*v[2] + v[3]*v[3];
#pragma unroll
  for (int o = 32; o; o >>= 1) { s += __shfl_down(s, o); ss += __shfl_down(ss, o); }
  __shared__ float red[8];
  if ((t & 63) == 0) { red[(t >> 6) * 2] = s; red[(t >> 6) * 2 + 1] = ss; }
  __syncthreads();
  s  = red[0] + red[2] + red[4] + red[6];
  ss = red[1] + red[3] + red[5] + red[7];
  float mu = s * (1.f / HDIM);
  float rstd = rsqrtf(ss * (1.f / HDIM) - mu * mu + LN_EPS);
  f4 gv = ((const f4*)g)[t], bv = ((const f4*)b)[t];
  f4 o;
#pragma unroll
  for (int i = 0; i < 4; i++) o[i] = (v[i] - mu) * rstd * gv[i] + bv[i];
  ((f4*)(out + (size_t)row * HDIM))[t] = o;
}

// ---------------- fp32 GEMM: C[M,N] = A[M,K] * B[N,K]^T (+resid) ----------------
// tile 128x64, 256 threads, per-thread 8x4
__global__ __launch_bounds__(256) void k_gemm_f32(
    const float* __restrict__ A, const float* __restrict__ B,
    float* __restrict__ C, const float* __restrict__ resid,
    float* __restrict__ C2, int M, int N, int K) {
  __shared__ float As[16][132];
  __shared__ float Bs[16][68];
  int m0 = blockIdx.y * 128, n0 = blockIdx.x * 64;
  int t = threadIdx.x;
  int tx = t & 15, ty = t >> 4;          // tx: 16 col groups of 4, ty: 16 row groups of 8
  int srow = t >> 2, skq = t & 3;        // A staging
  int sn = t & 63, skb = t >> 6;         // B staging
  float acc[8][4] = {};
  for (int k0 = 0; k0 < K; k0 += 16) {
    __syncthreads();
#pragma unroll
    for (int hh = 0; hh < 2; hh++) {
      int r = srow + hh * 64;
      f4 va = *(const f4*)(A + (size_t)(m0 + r) * K + k0 + skq * 4);
      As[skq*4+0][r] = va[0]; As[skq*4+1][r] = va[1];
      As[skq*4+2][r] = va[2]; As[skq*4+3][r] = va[3];
    }
    {
      f4 vb = *(const f4*)(B + (size_t)(n0 + sn) * K + k0 + skb * 4);
      Bs[skb*4+0][sn] = vb[0]; Bs[skb*4+1][sn] = vb[1];
      Bs[skb*4+2][sn] = vb[2]; Bs[skb*4+3][sn] = vb[3];
    }
    __syncthreads();
#pragma unroll 4
    for (int kk = 0; kk < 16; kk++) {
      f4 a0 = *(const f4*)&As[kk][ty * 8];
      f4 a1 = *(const f4*)&As[kk][ty * 8 + 4];
      f4 b0 = *(const f4*)&Bs[kk][tx * 4];
      float a[8] = {a0[0],a0[1],a0[2],a0[3],a1[0],a1[1],a1[2],a1[3]};
#pragma unroll
      for (int i = 0; i < 8; i++)
#pragma unroll
        for (int j = 0; j < 4; j++)
          acc[i][j] = fmaf(a[i], b0[j], acc[i][j]);
    }
  }
#pragma unroll
  for (int i = 0; i < 8; i++) {
    size_t roff = (size_t)(m0 + ty * 8 + i) * N + n0 + tx * 4;
    f4 o = {acc[i][0], acc[i][1], acc[i][2], acc[i][3]};
    if (resid) {
      f4 rv = *(const f4*)(resid + roff);
      o[0] += rv[0]; o[1] += rv[1]; o[2] += rv[2]; o[3] += rv[3];
    }
    if (C)  *(f4*)(C + roff) = o;
    if (C2) *(f4*)(C2 + roff) = o;
  }
}

// ---------------- fp32 flash attention (causal) ----------------
// block: one (b,h) pair, 64 q-rows. threads: (qr, dq) = (t>>2, t&3), dq owns 16 of 64 dims
__global__ __launch_bounds__(256) void k_attn(
    const float* __restrict__ qf, const float* __restrict__ kf,
    const float* __restrict__ vf, float* __restrict__ of) {
  int qt = blockIdx.x, bh = blockIdx.y;
  int bb = bh >> 4, hh = bh & 15;
  int t = threadIdx.x;
  int qr = t >> 2, dq = t & 3;
  int qrow = qt * 64 + qr;
  const size_t base = ((size_t)bb * SEQ) * HDIM + hh * DHEAD;
  float q[16], o[16];
#pragma unroll
  for (int i = 0; i < 16; i++) o[i] = 0.f;
  {
    const float* qp = qf + base + (size_t)qrow * HDIM + dq * 16;
#pragma unroll
    for (int i = 0; i < 4; i++) {
      f4 tmp = *(const f4*)(qp + 4 * i);
      q[4*i] = tmp[0]; q[4*i+1] = tmp[1]; q[4*i+2] = tmp[2]; q[4*i+3] = tmp[3];
    }
  }
  float m = -1e30f, l = 0.f;
  __shared__ float Ks[32][64], Vs[32][64];
  int nkv = (qt + 1) * 2;
  for (int kt = 0; kt < nkv; kt++) {
    __syncthreads();
#pragma unroll
    for (int c = 0; c < 2; c++) {
      int idx = c * 256 + t;
      int r = idx >> 4, c4 = idx & 15;
      *(f4*)&Ks[r][c4 * 4] = *(const f4*)(kf + base + (size_t)(kt * 32 + r) * HDIM + c4 * 4);
      *(f4*)&Vs[r][c4 * 4] = *(const f4*)(vf + base + (size_t)(kt * 32 + r) * HDIM + c4 * 4);
    }
    __syncthreads();
    float sv[32];
#pragma unroll
    for (int kk = 0; kk < 32; kk++) {
      const float* kr = &Ks[kk][dq * 16];
      float p = 0.f;
#pragma unroll
      for (int i = 0; i < 16; i++) p = fmaf(q[i], kr[i], p);
      p += __shfl_xor(p, 1);
      p += __shfl_xor(p, 2);
      sv[kk] = (kt * 32 + kk <= qrow) ? p * 0.125f : -1e30f;
    }
    float tm = sv[0];
#pragma unroll
    for (int kk = 1; kk < 32; kk++) tm = fmaxf(tm, sv[kk]);
    float mn = fmaxf(m, tm);
    float sc = __expf(m - mn);
    l *= sc;
#pragma unroll
    for (int i = 0; i < 16; i++) o[i] *= sc;
#pragma unroll
    for (int kk = 0; kk < 32; kk++) {
      float p = __expf(sv[kk] - mn);
      l += p;
      const float* vr = &Vs[kk][dq * 16];
#pragma unroll
      for (int i = 0; i < 16; i++) o[i] = fmaf(p, vr[i], o[i]);
    }
    m = mn;
  }
  float inv = 1.f / l;
  float* op = of + base + (size_t)qrow * HDIM + dq * 16;
#pragma unroll
  for (int i = 0; i < 4; i++) {
    f4 w = {o[4*i] * inv, o[4*i+1] * inv, o[4*i+2] * inv, o[4*i+3] * inv};
    *(f4*)(op + 4 * i) = w;
  }
}

// ---------------- LN2 + router (fp32 logits, top-2, usage) ----------------
// ctrl layout: [0..7] cnt, [8..15] offs, [16..23] cursor, [24..31] usage(float)
__global__ __launch_bounds__(256) void k_ln2_router(
    const float* __restrict__ x2, const float* __restrict__ g,
    const float* __restrict__ b, const float* __restrict__ Wr,
    ushortT* __restrict__ h2b, int* __restrict__ sel, float* __restrict__ selw,
    int* __restrict__ ctrl) {
  int row = blockIdx.x, t = threadIdx.x;
  f4 v = ((const f4*)(x2 + (size_t)row * HDIM))[t];
  float s  = v[0] + v[1] + v[2] + v[3];
  float ss = v[0]*v[0] + v[1]*v[1] + v[2]*v[2] + v[3]*v[3];
#pragma unroll
  for (int o = 32; o; o >>= 1) { s += __shfl_down(s, o); ss += __shfl_down(ss, o); }
  __shared__ float red[8];
  __shared__ float wlog[4][8];
  if ((t & 63) == 0) { red[(t >> 6) * 2] = s; red[(t >> 6) * 2 + 1] = ss; }
  __syncthreads();
  s  = red[0] + red[2] + red[4] + red[6];
  ss = red[1] + red[3] + red[5] + red[7];
  float mu = s * (1.f / HDIM);
  float rstd = rsqrtf(ss * (1.f / HDIM) - mu * mu + LN_EPS);
  f4 gv = ((const f4*)g)[t], bv = ((const f4*)b)[t];
  float hn[4];
#pragma unroll
  for (int i = 0; i < 4; i++) hn[i] = (v[i] - mu) * rstd * gv[i] + bv[i];
  uint2 pk;
  pk.x = (unsigned)f2bf(hn[0]) | ((unsigned)f2bf(hn[1]) << 16);
  pk.y = (unsigned)f2bf(hn[2]) | ((unsigned)f2bf(hn[3]) << 16);
  ((uint2*)(h2b + (size_t)row * HDIM))[t] = pk;
  float part[8];
#pragma unroll
  for (int e = 0; e < 8; e++) {
    f4 w = ((const f4*)(Wr + (size_t)e * HDIM))[t];
    part[e] = hn[0]*w[0] + hn[1]*w[1] + hn[2]*w[2] + hn[3]*w[3];
  }
#pragma unroll
  for (int o = 32; o; o >>= 1)
#pragma unroll
    for (int e = 0; e < 8; e++) part[e] += __shfl_down(part[e], o);
  if ((t & 63) == 0)
#pragma unroll
    for (int e = 0; e < 8; e++) wlog[t >> 6][e] = part[e];
  __syncthreads();
  if (t == 0) {
    float lg[8];
#pragma unroll
    for (int e = 0; e < 8; e++) lg[e] = wlog[0][e] + wlog[1][e] + wlog[2][e] + wlog[3][e];
    int i0 = 0;
    for (int e = 1; e < 8; e++) if (lg[e] > lg[i0]) i0 = e;
    int i1 = -1;
    for (int e = 0; e < 8; e++) if (e != i0 && (i1 < 0 || lg[e] > lg[i1])) i1 = e;
    float d = __expf(lg[i1] - lg[i0]);
    float w0 = 1.f / (1.f + d);
    sel[row * 2] = i0; sel[row * 2 + 1] = i1;
    selw[row * 2] = w0; selw[row * 2 + 1] = d * w0;
    atomicAdd(&ctrl[i0], 1);
    atomicAdd(&ctrl[i1], 1);
    float mx = lg[i0], se = 0.f, p[8];
#pragma unroll
    for (int e = 0; e < 8; e++) { p[e] = __expf(lg[e] - mx); se += p[e]; }
    float inv = 1.f / se;
    float* usage = (float*)(ctrl + 24);
#pragma unroll
    for (int e = 0; e < 8; e++) atomicAdd(&usage[e], p[e] * inv);
  }
}

__global__ void k_offsets(int* ctrl) {
  if (threadIdx.x == 0) {
    int s = 0;
    for (int e = 0; e < 8; e++) { ctrl[8 + e] = s; ctrl[16 + e] = s; s += ctrl[e]; }
  }
}

__global__ __launch_bounds__(256) void k_scatter(
    const int* __restrict__ sel, const float* __restrict__ selw,
    int* __restrict__ ctrl, int* __restrict__ slot_tok, float* __restrict__ slot_w) {
  int n = blockIdx.x * 256 + threadIdx.x;
#pragma unroll
  for (int j = 0; j < 2; j++) {
    int e = sel[n * 2 + j];
    int pos = atomicAdd(&ctrl[16 + e], 1);
    slot_tok[pos] = n;
    slot_w[pos] = selw[n * 2 + j];
  }
}

// ---------------- MoE GEMM1: hgate = silu(X W1^T) * (X W3^T), bf16 MFMA ----------------
// block tile: 128 slots x 64 f, BK=64. 4 waves (2x2), wave tile 64x32 per B matrix.
__global__ __launch_bounds__(256) void k_moe_gemm1(
    const ushortT* __restrict__ h2b, const float* __restrict__ W1,
    const float* __restrict__ W3, const int* __restrict__ ctrl,
    const int* __restrict__ slot_tok, ushortT* __restrict__ hbuf) {
  int e = blockIdx.z, mt = blockIdx.y, nt = blockIdx.x;
  int ce = ctrl[e];
  int m0 = mt * 128;
  if (m0 >= ce) return;
  int oe = ctrl[8 + e];
  int f0 = nt * 64;
  const float* B1 = W1 + (size_t)e * FDIM * HDIM + (size_t)f0 * HDIM;
  const float* B3 = W3 + (size_t)e * FDIM * HDIM + (size_t)f0 * HDIM;
  __shared__ ushortT As[128][64];
  __shared__ ushortT B1s[64][64];
  __shared__ ushortT B3s[64][64];
  int t = threadIdx.x;
  int l = t & 63, wid = t >> 6;
  int lr = l & 15, lg = l >> 4;
  int wm = (wid >> 1) * 64, wn = (wid & 1) * 32;
  const ushortT* aptr[4];
#pragma unroll
  for (int c = 0; c < 4; c++) {
    int id = c * 256 + t;
    int r = id >> 3, c8 = id & 7;
    int gr = m0 + r;
    if (gr < ce) {
      int tok = slot_tok[oe + gr];
      aptr[c] = h2b + (size_t)tok * HDIM + c8 * 8;
    } else aptr[c] = nullptr;
  }
  v4f acc1[4][2] = {};
  v4f acc3[4][2] = {};
  for (int k0 = 0; k0 < HDIM; k0 += 64) {
    __syncthreads();
#pragma unroll
    for (int c = 0; c < 4; c++) {
      int id = c * 256 + t;
      int r = id >> 3, c8 = id & 7;
      frag8 v = {};
      if (aptr[c]) v = *(const frag8*)(aptr[c] + k0);
      *(frag8*)&As[r][((c8 ^ (r & 7)) * 8)] = v;
    }
#pragma unroll
    for (int c = 0; c < 2; c++) {
      int id = c * 256 + t;
      int r = id >> 3, c8 = id & 7;
      const float* p = B1 + (size_t)r * HDIM + k0 + c8 * 8;
      f4 u0 = *(const f4*)p, u1 = *(const f4*)(p + 4);
      frag8 v;
      v[0]=(short)f2bf(u0[0]); v[1]=(short)f2bf(u0[1]); v[2]=(short)f2bf(u0[2]); v[3]=(short)f2bf(u0[3]);
      v[4]=(short)f2bf(u1[0]); v[5]=(short)f2bf(u1[1]); v[6]=(short)f2bf(u1[2]); v[7]=(short)f2bf(u1[3]);
      *(frag8*)&B1s[r][((c8 ^ (r & 7)) * 8)] = v;
      p = B3 + (size_t)r * HDIM + k0 + c8 * 8;
      u0 = *(const f4*)p; u1 = *(const f4*)(p + 4);
      v[0]=(short)f2bf(u0[0]); v[1]=(short)f2bf(u0[1]); v[2]=(short)f2bf(u0[2]); v[3]=(short)f2bf(u0[3]);
      v[4]=(short)f2bf(u1[0]); v[5]=(short)f2bf(u1[1]); v[6]=(short)f2bf(u1[2]); v[7]=(short)f2bf(u1[3]);
      *(frag8*)&B3s[r][((c8 ^ (r & 7)) * 8)] = v;
    }
    __syncthreads();
#pragma unroll
    for (int kk = 0; kk < 2; kk++) {
      frag8 a[4], b1[2], b3[2];
#pragma unroll
      for (int mi = 0; mi < 4; mi++) {
        int rr = wm + mi * 16 + lr;
        a[mi] = *(const frag8*)&As[rr][(((kk * 4 + lg) ^ (rr & 7)) * 8)];
      }
#pragma unroll
      for (int ni = 0; ni < 2; ni++) {
        int n = wn + ni * 16 + lr;
        int cc = ((kk * 4 + lg) ^ (n & 7)) * 8;
        b1[ni] = *(const frag8*)&B1s[n][cc];
        b3[ni] = *(const frag8*)&B3s[n][cc];
      }
#pragma unroll
      for (int mi = 0; mi < 4; mi++)
#pragma unroll
        for (int ni = 0; ni < 2; ni++) {
          acc1[mi][ni] = __builtin_amdgcn_mfma_f32_16x16x32_bf16(a[mi], b1[ni], acc1[mi][ni], 0, 0, 0);
          acc3[mi][ni] = __builtin_amdgcn_mfma_f32_16x16x32_bf16(a[mi], b3[ni], acc3[mi][ni], 0, 0, 0);
        }
    }
  }
#pragma unroll
  for (int mi = 0; mi < 4; mi++)
#pragma unroll
    for (int r = 0; r < 4; r++) {
      int grow = m0 + wm + mi * 16 + lg * 4 + r;
      if (grow < ce) {
        ushortT* hp = hbuf + (size_t)(oe + grow) * FDIM + f0 + wn;
#pragma unroll
        for (int ni = 0; ni < 2; ni++) {
          float z1 = acc1[mi][ni][r], z3 = acc3[mi][ni][r];
          float hg = z1 / (1.f + __expf(-z1)) * z3;
          hp[ni * 16 + lr] = f2bf(hg);
        }
      }
    }
}

// ---------------- MoE GEMM2: out += w * (hgate W2^T), scatter-atomic ----------------
// block tile: 128 slots x 128 h, BK=64. wave tile 64x64.
__global__ __launch_bounds__(256) void k_moe_gemm2(
    const ushortT* __restrict__ hbuf, const float* __restrict__ W2,
    const int* __restrict__ ctrl, const int* __restrict__ slot_tok,
    const float* __restrict__ slot_w, float* __restrict__ outp) {
  int e = blockIdx.z, mt = blockIdx.y, nt = blockIdx.x;
  int ce = ctrl[e];
  int m0 = mt * 128;
  if (m0 >= ce) return;
  int oe = ctrl[8 + e];
  int h0 = nt * 128;
  const float* Bw = W2 + (size_t)e * HDIM * FDIM + (size_t)h0 * FDIM;
  __shared__ ushortT As[128][64];
  __shared__ ushortT Bs[128][64];
  int t = threadIdx.x;
  int l = t & 63, wid = t >> 6;
  int lr = l & 15, lg = l >> 4;
  int wm = (wid >> 1) * 64, wn = (wid & 1) * 64;
  v4f acc[4][4] = {};
  for (int k0 = 0; k0 < FDIM; k0 += 64) {
    __syncthreads();
#pragma unroll
    for (int c = 0; c < 4; c++) {
      int id = c * 256 + t;
      int r = id >> 3, c8 = id & 7;
      frag8 v = {};
      if (m0 + r < ce) v = *(const frag8*)(hbuf + (size_t)(oe + m0 + r) * FDIM + k0 + c8 * 8);
      *(frag8*)&As[r][((c8 ^ (r & 7)) * 8)] = v;
    }
#pragma unroll
    for (int c = 0; c < 4; c++) {
      int id = c * 256 + t;
      int r = id >> 3, c8 = id & 7;
      const float* p = Bw + (size_t)r * FDIM + k0 + c8 * 8;
      f4 u0 = *(const f4*)p, u1 = *(const f4*)(p + 4);
      frag8 v;
      v[0]=(short)f2bf(u0[0]); v[1]=(short)f2bf(u0[1]); v[2]=(short)f2bf(u0[2]); v[3]=(short)f2bf(u0[3]);
      v[4]=(short)f2bf(u1[0]); v[5]=(short)f2bf(u1[1]); v[6]=(short)f2bf(u1[2]); v[7]=(short)f2bf(u1[3]);
      *(frag8*)&Bs[r][((c8 ^ (r & 7)) * 8)] = v;
    }
    __syncthreads();
#pragma unroll
    for (int kk = 0; kk < 2; kk++) {
      frag8 a[4], b[4];
#pragma unroll
      for (int mi = 0; mi < 4; mi++) {
        int rr = wm + mi * 16 + lr;
        a[mi] = *(const frag8*)&As[rr][(((kk * 4 + lg) ^ (rr & 7)) * 8)];
      }
#pragma unroll
      for (int ni = 0; ni < 4; ni++) {
        int n = wn + ni * 16 + lr;
        b[ni] = *(const frag8*)&Bs[n][(((kk * 4 + lg) ^ (n & 7)) * 8)];
      }
#pragma unroll
      for (int mi = 0; mi < 4; mi++)
#pragma unroll
        for (int ni = 0; ni < 4; ni++)
          acc[mi][ni] = __builtin_amdgcn_mfma_f32_16x16x32_bf16(a[mi], b[ni], acc[mi][ni], 0, 0, 0);
    }
  }
#pragma unroll
  for (int mi = 0; mi < 4; mi++)
#pragma unroll
    for (int r = 0; r < 4; r++) {
      int grow = m0 + wm + mi * 16 + lg * 4 + r;
      if (grow < ce) {
        int slot = oe + grow;
        int tok = slot_tok[slot];
        float w = slot_w[slot];
        float* op = outp + (size_t)tok * HDIM + h0 + wn;
#pragma unroll
        for (int ni = 0; ni < 4; ni++)
          atomicAdd(op + ni * 16 + lr, w * acc[mi][ni][r]);
      }
    }
}

__global__ void k_lb(const int* ctrl, float* out) {
  if (threadIdx.x == 0) {
    const float* usage = (const float*)(ctrl + 24);
    float s = 0.f;
    for (int e = 0; e < 8; e++) { float u = usage[e] * (1.f / NTOK); s += u * u; }
    out[0] = 8.f * s;
  }
}

// ---------------- launch ----------------
extern "C" void kernel_launch(void* const* d_in, const int* in_sizes, int n_in,
                              void* d_out, int out_size, void* d_ws, size_t ws_size,
                              hipStream_t stream) {
  const float* x  = (const float*)d_in[0];
  const float* Wq = (const float*)d_in[1];
  const float* Wk = (const float*)d_in[2];
  const float* Wv = (const float*)d_in[3];
  const float* Wo = (const float*)d_in[4];
  const float* g1 = (const float*)d_in[5];
  const float* b1 = (const float*)d_in[6];
  const float* g2 = (const float*)d_in[7];
  const float* b2 = (const float*)d_in[8];
  const float* Wr = (const float*)d_in[9];
  const float* W1 = (const float*)d_in[10];
  const float* W2 = (const float*)d_in[11];
  const float* W3 = (const float*)d_in[12];
  float* outp = (float*)d_out;

  const size_t NHTOT = (size_t)NTOK * HDIM;  // 2M elements
  char* ws = (char*)d_ws;
  float* h1f   = (float*)ws;                 // 8 MB  (reused as attnf)
  float* qf    = h1f + NHTOT;                // 8 MB  (reused as x2)
  float* kf    = qf + NHTOT;                 // 8 MB  (reused as h2b)
  float* vf    = kf + NHTOT;                 // 8 MB
  float* attnf = h1f;
  float* x2    = qf;
  ushortT* h2b = (ushortT*)kf;
  ushortT* hbuf = (ushortT*)(vf + NHTOT);    // 4096 x 4096 bf16 = 32 MB
  int*   slot_tok = (int*)(hbuf + (size_t)4096 * FDIM);
  float* slot_w   = (float*)(slot_tok + 4096);
  int*   sel      = (int*)(slot_w + 4096);
  float* selw     = (float*)(sel + 2 * NTOK);
  int*   ctrl     = (int*)(selw + 2 * NTOK);

  k_zero<<<dim3(1), dim3(64), 0, stream>>>(ctrl);
  k_ln<<<dim3(NTOK), dim3(256), 0, stream>>>(x, g1, b1, h1f);

  dim3 gg(HDIM / 64, NTOK / 128);
  k_gemm_f32<<<gg, dim3(256), 0, stream>>>(h1f, Wq, qf, nullptr, nullptr, NTOK, HDIM, HDIM);
  k_gemm_f32<<<gg, dim3(256), 0, stream>>>(h1f, Wk, kf, nullptr, nullptr, NTOK, HDIM, HDIM);
  k_gemm_f32<<<gg, dim3(256), 0, stream>>>(h1f, Wv, vf, nullptr, nullptr, NTOK, HDIM, HDIM);

  k_attn<<<dim3(SEQ / 64, 32), dim3(256), 0, stream>>>(qf, kf, vf, attnf);

  k_gemm_f32<<<gg, dim3(256), 0, stream>>>(attnf, Wo, x2, x, outp, NTOK, HDIM, HDIM);

  k_ln2_router<<<dim3(NTOK), dim3(256), 0, stream>>>(x2, g2, b2, Wr, h2b, sel, selw, ctrl);
  k_offsets<<<dim3(1), dim3(1), 0, stream>>>(ctrl);
  k_scatter<<<dim3(8), dim3(256), 0, stream>>>(sel, selw, ctrl, slot_tok, slot_w);

  k_moe_gemm1<<<dim3(FDIM / 64, 16, 8), dim3(256), 0, stream>>>(h2b, W1, W3, ctrl, slot_tok, hbuf);
  k_moe_gemm2<<<dim3(HDIM / 128, 16, 8), dim3(256), 0, stream>>>(hbuf, W2, ctrl, slot_tok, slot_w, outp);

  k_lb<<<dim3(1), dim3(64), 0, stream>>>(ctrl, outp + NHTOT);
}

// Round 4
// 1061.089 us; speedup vs baseline: 1.4649x; 1.4649x over previous
//
#include <hip/hip_runtime.h>
#include <hip/hip_bf16.h>

#define HDIM 1024
#define NTOK 2048
#define NHEAD 16
#define DHEAD 64
#define SEQ 1024
#define NEXP 8
#define FDIM 4096
#define LN_EPS 1e-5f

using f4    = __attribute__((ext_vector_type(4))) float;
using frag8 = __attribute__((ext_vector_type(8))) short;
using v4f   = __attribute__((ext_vector_type(4))) float;
typedef unsigned short ushortT;

__device__ __forceinline__ unsigned short f2bf(float x) {
  unsigned int u = __float_as_uint(x);
  unsigned int r = (u + 0x7fffu + ((u >> 16) & 1u)) >> 16;
  return (unsigned short)r;
}

// split x into hi (bf16) + lo (bf16 of residual); x ~= hi + lo to ~2^-18
__device__ __forceinline__ void splitbf(float x, ushortT& h, ushortT& lo) {
  h = f2bf(x);
  float hf = __uint_as_float((unsigned)h << 16);
  lo = f2bf(x - hf);
}

// ---------------- zero control block ----------------
__global__ void k_zero(int* ctrl) {
  if (threadIdx.x < 32) ctrl[threadIdx.x] = 0;
}

// ---------------- LayerNorm (fp32 in -> fp32 out) ----------------
__global__ __launch_bounds__(256) void k_ln(
    const float* __restrict__ x, const float* __restrict__ g,
    const float* __restrict__ b, float* __restrict__ out) {
  int row = blockIdx.x, t = threadIdx.x;
  f4 v = ((const f4*)(x + (size_t)row * HDIM))[t];
  float s  = v[0] + v[1] + v[2] + v[3];
  float ss = v[0]*v[0] + v[1]*v[1] + v[2]*v[2] + v[3]*v[3];
#pragma unroll
  for (int o = 32; o; o >>= 1) { s += __shfl_down(s, o); ss += __shfl_down(ss, o); }
  __shared__ float red[8];
  if ((t & 63) == 0) { red[(t >> 6) * 2] = s; red[(t >> 6) * 2 + 1] = ss; }
  __syncthreads();
  s  = red[0] + red[2] + red[4] + red[6];
  ss = red[1] + red[3] + red[5] + red[7];
  float mu = s * (1.f / HDIM);
  float rstd = rsqrtf(ss * (1.f / HDIM) - mu * mu + LN_EPS);
  f4 gv = ((const f4*)g)[t], bv = ((const f4*)b)[t];
  f4 o;
#pragma unroll
  for (int i = 0; i < 4; i++) o[i] = (v[i] - mu) * rstd * gv[i] + bv[i];
  ((f4*)(out + (size_t)row * HDIM))[t] = o;
}

// ---------------- bf16x3 MFMA GEMM: C[M,N]=A[M,K]*B[N,K]^T, fp32-accurate ----
// BM=128, BN=64, BK=64. 4 waves, each 32 rows x 64 cols (mi=2, ni=4).
// grid.z selects (B,C) among up to 3; resid/Cdup used for Wo launch.
__global__ __launch_bounds__(256) void k_gemm3(
    const float* __restrict__ A,
    const float* __restrict__ B0, const float* __restrict__ B1, const float* __restrict__ B2,
    float* __restrict__ C0, float* __restrict__ C1, float* __restrict__ C2,
    const float* __restrict__ resid, float* __restrict__ Cdup) {
  const float* B = blockIdx.z == 0 ? B0 : (blockIdx.z == 1 ? B1 : B2);
  float* C = blockIdx.z == 0 ? C0 : (blockIdx.z == 1 ? C1 : C2);
  int m0 = blockIdx.y * 128, n0 = blockIdx.x * 64;
  __shared__ __align__(16) ushortT Ah[128][72], Al[128][72];
  __shared__ __align__(16) ushortT Bh[64][72],  Bl[64][72];
  int t = threadIdx.x, w = t >> 6, l = t & 63, lr = l & 15, lg = l >> 4;
  v4f acc[2][4] = {};
  for (int k0 = 0; k0 < HDIM; k0 += 64) {
    __syncthreads();
#pragma unroll
    for (int c = 0; c < 4; c++) {
      int id = c * 256 + t, r = id >> 3, c8 = id & 7;
      const float* p = A + (size_t)(m0 + r) * HDIM + k0 + c8 * 8;
      float tmp[8];
      *(f4*)&tmp[0] = *(const f4*)p; *(f4*)&tmp[4] = *(const f4*)(p + 4);
      frag8 vh, vl;
#pragma unroll
      for (int j = 0; j < 8; j++) {
        ushortT h, lo; splitbf(tmp[j], h, lo);
        vh[j] = (short)h; vl[j] = (short)lo;
      }
      *(frag8*)&Ah[r][c8 * 8] = vh; *(frag8*)&Al[r][c8 * 8] = vl;
    }
#pragma unroll
    for (int c = 0; c < 2; c++) {
      int id = c * 256 + t, r = id >> 3, c8 = id & 7;
      const float* p = B + (size_t)(n0 + r) * HDIM + k0 + c8 * 8;
      float tmp[8];
      *(f4*)&tmp[0] = *(const f4*)p; *(f4*)&tmp[4] = *(const f4*)(p + 4);
      frag8 vh, vl;
#pragma unroll
      for (int j = 0; j < 8; j++) {
        ushortT h, lo; splitbf(tmp[j], h, lo);
        vh[j] = (short)h; vl[j] = (short)lo;
      }
      *(frag8*)&Bh[r][c8 * 8] = vh; *(frag8*)&Bl[r][c8 * 8] = vl;
    }
    __syncthreads();
#pragma unroll
    for (int ks = 0; ks < 2; ks++) {
      frag8 ah_[2], al_[2], bh_[4], bl_[4];
#pragma unroll
      for (int mi = 0; mi < 2; mi++) {
        ah_[mi] = *(const frag8*)&Ah[w * 32 + mi * 16 + lr][ks * 32 + lg * 8];
        al_[mi] = *(const frag8*)&Al[w * 32 + mi * 16 + lr][ks * 32 + lg * 8];
      }
#pragma unroll
      for (int ni = 0; ni < 4; ni++) {
        bh_[ni] = *(const frag8*)&Bh[ni * 16 + lr][ks * 32 + lg * 8];
        bl_[ni] = *(const frag8*)&Bl[ni * 16 + lr][ks * 32 + lg * 8];
      }
#pragma unroll
      for (int mi = 0; mi < 2; mi++)
#pragma unroll
        for (int ni = 0; ni < 4; ni++) {
          acc[mi][ni] = __builtin_amdgcn_mfma_f32_16x16x32_bf16(ah_[mi], bh_[ni], acc[mi][ni], 0, 0, 0);
          acc[mi][ni] = __builtin_amdgcn_mfma_f32_16x16x32_bf16(ah_[mi], bl_[ni], acc[mi][ni], 0, 0, 0);
          acc[mi][ni] = __builtin_amdgcn_mfma_f32_16x16x32_bf16(al_[mi], bh_[ni], acc[mi][ni], 0, 0, 0);
        }
    }
  }
#pragma unroll
  for (int mi = 0; mi < 2; mi++)
#pragma unroll
    for (int ni = 0; ni < 4; ni++)
#pragma unroll
      for (int rr = 0; rr < 4; rr++) {
        int row = m0 + w * 32 + mi * 16 + lg * 4 + rr;
        int col = n0 + ni * 16 + lr;
        float v = acc[mi][ni][rr];
        if (resid) v += resid[(size_t)row * HDIM + col];
        C[(size_t)row * HDIM + col] = v;
        if (Cdup) Cdup[(size_t)row * HDIM + col] = v;
      }
}

// ---------------- MFMA flash attention (causal), bf16x3-accurate -----------
// block = (qt: 64 q-rows, bh). 4 waves x 16 q-rows. kv-tile 64.
__global__ __launch_bounds__(256) void k_attn_mfma(
    const float* __restrict__ qf, const float* __restrict__ kf,
    const float* __restrict__ vf, float* __restrict__ of) {
  int qt = blockIdx.x, bh = blockIdx.y;
  int bb = bh >> 4, hh = bh & 15;
  const size_t base = ((size_t)bb * SEQ) * HDIM + (size_t)hh * DHEAD;
  __shared__ __align__(16) ushortT Kh[64][72], Kl[64][72];
  __shared__ __align__(16) ushortT Vh[64][72], Vl[64][72];
  __shared__ __align__(16) ushortT Ph[64][72], Pl[64][72];
  int t = threadIdx.x, w = t >> 6, l = t & 63, lr = l & 15, lg = l >> 4;

  // stage Q * 0.125 into Ph/Pl, then pull frags to registers
#pragma unroll
  for (int c = 0; c < 2; c++) {
    int id = c * 256 + t, r = id >> 3, c8 = id & 7;
    const float* p = qf + base + (size_t)(qt * 64 + r) * HDIM + c8 * 8;
    float tmp[8];
    *(f4*)&tmp[0] = *(const f4*)p; *(f4*)&tmp[4] = *(const f4*)(p + 4);
    frag8 vh, vl;
#pragma unroll
    for (int j = 0; j < 8; j++) {
      ushortT h, lo; splitbf(tmp[j] * 0.125f, h, lo);
      vh[j] = (short)h; vl[j] = (short)lo;
    }
    *(frag8*)&Ph[r][c8 * 8] = vh; *(frag8*)&Pl[r][c8 * 8] = vl;
  }
  __syncthreads();
  frag8 qh[2], ql[2];
#pragma unroll
  for (int ks = 0; ks < 2; ks++) {
    qh[ks] = *(const frag8*)&Ph[w * 16 + lr][ks * 32 + lg * 8];
    ql[ks] = *(const frag8*)&Pl[w * 16 + lr][ks * 32 + lg * 8];
  }

  float m[4], lsum[4];
  v4f o[4] = {};
#pragma unroll
  for (int rr = 0; rr < 4; rr++) { m[rr] = -1e30f; lsum[rr] = 0.f; }

  int nkv = qt + 1;
  for (int kt = 0; kt < nkv; kt++) {
    __syncthreads();
    // stage K hi/lo
#pragma unroll
    for (int c = 0; c < 2; c++) {
      int id = c * 256 + t, r = id >> 3, c8 = id & 7;
      const float* p = kf + base + (size_t)(kt * 64 + r) * HDIM + c8 * 8;
      float tmp[8];
      *(f4*)&tmp[0] = *(const f4*)p; *(f4*)&tmp[4] = *(const f4*)(p + 4);
      frag8 vh, vl;
#pragma unroll
      for (int j = 0; j < 8; j++) {
        ushortT h, lo; splitbf(tmp[j], h, lo);
        vh[j] = (short)h; vl[j] = (short)lo;
      }
      *(frag8*)&Kh[r][c8 * 8] = vh; *(frag8*)&Kl[r][c8 * 8] = vl;
    }
    // stage V^T hi/lo (transpose in addressing; coalesced global reads)
#pragma unroll
    for (int i = 0; i < 4; i++) {
      int id = i * 256 + t, d = id & 63, kv4 = id >> 6;  // kv4: 0..15
      ushortT hh4[4], ll4[4];
#pragma unroll
      for (int j = 0; j < 4; j++) {
        float x = vf[base + (size_t)(kt * 64 + kv4 * 4 + j) * HDIM + d];
        splitbf(x, hh4[j], ll4[j]);
      }
      uint2 ph2, pl2;
      ph2.x = hh4[0] | ((unsigned)hh4[1] << 16); ph2.y = hh4[2] | ((unsigned)hh4[3] << 16);
      pl2.x = ll4[0] | ((unsigned)ll4[1] << 16); pl2.y = ll4[2] | ((unsigned)ll4[3] << 16);
      *(uint2*)&Vh[d][kv4 * 4] = ph2;
      *(uint2*)&Vl[d][kv4 * 4] = pl2;
    }
    __syncthreads();
    // QK^T (scores already scaled via Q)
    v4f s[4] = {};
#pragma unroll
    for (int ks = 0; ks < 2; ks++) {
#pragma unroll
      for (int ni = 0; ni < 4; ni++) {
        frag8 kh_ = *(const frag8*)&Kh[ni * 16 + lr][ks * 32 + lg * 8];
        frag8 kl_ = *(const frag8*)&Kl[ni * 16 + lr][ks * 32 + lg * 8];
        s[ni] = __builtin_amdgcn_mfma_f32_16x16x32_bf16(qh[ks], kh_, s[ni], 0, 0, 0);
        s[ni] = __builtin_amdgcn_mfma_f32_16x16x32_bf16(qh[ks], kl_, s[ni], 0, 0, 0);
        s[ni] = __builtin_amdgcn_mfma_f32_16x16x32_bf16(ql[ks], kh_, s[ni], 0, 0, 0);
      }
    }
    if (kt == qt) {  // diagonal tile: causal mask
      int qloc = w * 16 + lg * 4;
#pragma unroll
      for (int ni = 0; ni < 4; ni++) {
        int kv = ni * 16 + lr;
#pragma unroll
        for (int rr = 0; rr < 4; rr++)
          if (kv > qloc + rr) s[ni][rr] = -1e30f;
      }
    }
    // online softmax (row = 16 lr-lanes at fixed lg)
#pragma unroll
    for (int rr = 0; rr < 4; rr++) {
      float rm = fmaxf(fmaxf(s[0][rr], s[1][rr]), fmaxf(s[2][rr], s[3][rr]));
      rm = fmaxf(rm, __shfl_xor(rm, 1));
      rm = fmaxf(rm, __shfl_xor(rm, 2));
      rm = fmaxf(rm, __shfl_xor(rm, 4));
      rm = fmaxf(rm, __shfl_xor(rm, 8));
      float mn = fmaxf(m[rr], rm);
      float sc = __expf(m[rr] - mn);
      m[rr] = mn; lsum[rr] *= sc;
#pragma unroll
      for (int nd = 0; nd < 4; nd++) o[nd][rr] *= sc;
#pragma unroll
      for (int ni = 0; ni < 4; ni++) {
        float p = __expf(s[ni][rr] - mn);
        lsum[rr] += p;
        ushortT h, lo; splitbf(p, h, lo);
        int q = w * 16 + lg * 4 + rr, kv = ni * 16 + lr;
        Ph[q][kv] = h; Pl[q][kv] = lo;
      }
    }
    // PV (P rows are wave-local: no barrier needed)
#pragma unroll
    for (int ks = 0; ks < 2; ks++) {
      frag8 pa = *(const frag8*)&Ph[w * 16 + lr][ks * 32 + lg * 8];
      frag8 pb = *(const frag8*)&Pl[w * 16 + lr][ks * 32 + lg * 8];
#pragma unroll
      for (int nd = 0; nd < 4; nd++) {
        frag8 vhf = *(const frag8*)&Vh[nd * 16 + lr][ks * 32 + lg * 8];
        frag8 vlf = *(const frag8*)&Vl[nd * 16 + lr][ks * 32 + lg * 8];
        o[nd] = __builtin_amdgcn_mfma_f32_16x16x32_bf16(pa, vhf, o[nd], 0, 0, 0);
        o[nd] = __builtin_amdgcn_mfma_f32_16x16x32_bf16(pa, vlf, o[nd], 0, 0, 0);
        o[nd] = __builtin_amdgcn_mfma_f32_16x16x32_bf16(pb, vhf, o[nd], 0, 0, 0);
      }
    }
  }
#pragma unroll
  for (int rr = 0; rr < 4; rr++) {
    lsum[rr] += __shfl_xor(lsum[rr], 1);
    lsum[rr] += __shfl_xor(lsum[rr], 2);
    lsum[rr] += __shfl_xor(lsum[rr], 4);
    lsum[rr] += __shfl_xor(lsum[rr], 8);
    lsum[rr] = 1.f / lsum[rr];
  }
#pragma unroll
  for (int nd = 0; nd < 4; nd++)
#pragma unroll
    for (int rr = 0; rr < 4; rr++)
      of[base + (size_t)(qt * 64 + w * 16 + lg * 4 + rr) * HDIM + nd * 16 + lr] =
          o[nd][rr] * lsum[rr];
}

// ---------------- LN2 + router (fp32 logits, top-2, usage) ----------------
// ctrl layout: [0..7] cnt, [8..15] offs, [16..23] cursor, [24..31] usage(float)
__global__ __launch_bounds__(256) void k_ln2_router(
    const float* __restrict__ x2, const float* __restrict__ g,
    const float* __restrict__ b, const float* __restrict__ Wr,
    ushortT* __restrict__ h2b, int* __restrict__ sel, float* __restrict__ selw,
    int* __restrict__ ctrl) {
  int row = blockIdx.x, t = threadIdx.x;
  f4 v = ((const f4*)(x2 + (size_t)row * HDIM))[t];
  float s  = v[0] + v[1] + v[2] + v[3];
  float ss = v[0]*v[0] + v[1]*v[1] + v[2]*v[2] + v[3]*v[3];
#pragma unroll
  for (int o = 32; o; o >>= 1) { s += __shfl_down(s, o); ss += __shfl_down(ss, o); }
  __shared__ float red[8];
  __shared__ float wlog[4][8];
  if ((t & 63) == 0) { red[(t >> 6) * 2] = s; red[(t >> 6) * 2 + 1] = ss; }
  __syncthreads();
  s  = red[0] + red[2] + red[4] + red[6];
  ss = red[1] + red[3] + red[5] + red[7];
  float mu = s * (1.f / HDIM);
  float rstd = rsqrtf(ss * (1.f / HDIM) - mu * mu + LN_EPS);
  f4 gv = ((const f4*)g)[t], bv = ((const f4*)b)[t];
  float hn[4];
#pragma unroll
  for (int i = 0; i < 4; i++) hn[i] = (v[i] - mu) * rstd * gv[i] + bv[i];
  uint2 pk;
  pk.x = (unsigned)f2bf(hn[0]) | ((unsigned)f2bf(hn[1]) << 16);
  pk.y = (unsigned)f2bf(hn[2]) | ((unsigned)f2bf(hn[3]) << 16);
  ((uint2*)(h2b + (size_t)row * HDIM))[t] = pk;
  float part[8];
#pragma unroll
  for (int e = 0; e < 8; e++) {
    f4 w = ((const f4*)(Wr + (size_t)e * HDIM))[t];
    part[e] = hn[0]*w[0] + hn[1]*w[1] + hn[2]*w[2] + hn[3]*w[3];
  }
#pragma unroll
  for (int o = 32; o; o >>= 1)
#pragma unroll
    for (int e = 0; e < 8; e++) part[e] += __shfl_down(part[e], o);
  if ((t & 63) == 0)
#pragma unroll
    for (int e = 0; e < 8; e++) wlog[t >> 6][e] = part[e];
  __syncthreads();
  if (t == 0) {
    float lg[8];
#pragma unroll
    for (int e = 0; e < 8; e++) lg[e] = wlog[0][e] + wlog[1][e] + wlog[2][e] + wlog[3][e];
    int i0 = 0;
    for (int e = 1; e < 8; e++) if (lg[e] > lg[i0]) i0 = e;
    int i1 = -1;
    for (int e = 0; e < 8; e++) if (e != i0 && (i1 < 0 || lg[e] > lg[i1])) i1 = e;
    float d = __expf(lg[i1] - lg[i0]);
    float w0 = 1.f / (1.f + d);
    sel[row * 2] = i0; sel[row * 2 + 1] = i1;
    selw[row * 2] = w0; selw[row * 2 + 1] = d * w0;
    atomicAdd(&ctrl[i0], 1);
    atomicAdd(&ctrl[i1], 1);
    float mx = lg[i0], se = 0.f, p[8];
#pragma unroll
    for (int e = 0; e < 8; e++) { p[e] = __expf(lg[e] - mx); se += p[e]; }
    float inv = 1.f / se;
    float* usage = (float*)(ctrl + 24);
#pragma unroll
    for (int e = 0; e < 8; e++) atomicAdd(&usage[e], p[e] * inv);
  }
}

__global__ void k_offsets(int* ctrl) {
  if (threadIdx.x == 0) {
    int s = 0;
    for (int e = 0; e < 8; e++) { ctrl[8 + e] = s; ctrl[16 + e] = s; s += ctrl[e]; }
  }
}

__global__ __launch_bounds__(256) void k_scatter(
    const int* __restrict__ sel, const float* __restrict__ selw,
    int* __restrict__ ctrl, int* __restrict__ slot_tok, float* __restrict__ slot_w) {
  int n = blockIdx.x * 256 + threadIdx.x;
#pragma unroll
  for (int j = 0; j < 2; j++) {
    int e = sel[n * 2 + j];
    int pos = atomicAdd(&ctrl[16 + e], 1);
    slot_tok[pos] = n;
    slot_w[pos] = selw[n * 2 + j];
  }
}

// ---------------- MoE GEMM1: hgate = silu(X W1^T) * (X W3^T), bf16 MFMA ----
__global__ __launch_bounds__(256) void k_moe_gemm1(
    const ushortT* __restrict__ h2b, const float* __restrict__ W1,
    const float* __restrict__ W3, const int* __restrict__ ctrl,
    const int* __restrict__ slot_tok, ushortT* __restrict__ hbuf) {
  int e = blockIdx.z, mt = blockIdx.y, nt = blockIdx.x;
  int ce = ctrl[e];
  int m0 = mt * 128;
  if (m0 >= ce) return;
  int oe = ctrl[8 + e];
  int f0 = nt * 64;
  const float* B1 = W1 + (size_t)e * FDIM * HDIM + (size_t)f0 * HDIM;
  const float* B3 = W3 + (size_t)e * FDIM * HDIM + (size_t)f0 * HDIM;
  __shared__ ushortT As[128][64];
  __shared__ ushortT B1s[64][64];
  __shared__ ushortT B3s[64][64];
  int t = threadIdx.x;
  int l = t & 63, wid = t >> 6;
  int lr = l & 15, lg = l >> 4;
  int wm = (wid >> 1) * 64, wn = (wid & 1) * 32;
  const ushortT* aptr[4];
#pragma unroll
  for (int c = 0; c < 4; c++) {
    int id = c * 256 + t;
    int r = id >> 3, c8 = id & 7;
    int gr = m0 + r;
    if (gr < ce) {
      int tok = slot_tok[oe + gr];
      aptr[c] = h2b + (size_t)tok * HDIM + c8 * 8;
    } else aptr[c] = nullptr;
  }
  v4f acc1[4][2] = {};
  v4f acc3[4][2] = {};
  for (int k0 = 0; k0 < HDIM; k0 += 64) {
    __syncthreads();
#pragma unroll
    for (int c = 0; c < 4; c++) {
      int id = c * 256 + t;
      int r = id >> 3, c8 = id & 7;
      frag8 v = {};
      if (aptr[c]) v = *(const frag8*)(aptr[c] + k0);
      *(frag8*)&As[r][((c8 ^ (r & 7)) * 8)] = v;
    }
#pragma unroll
    for (int c = 0; c < 2; c++) {
      int id = c * 256 + t;
      int r = id >> 3, c8 = id & 7;
      const float* p = B1 + (size_t)r * HDIM + k0 + c8 * 8;
      f4 u0 = *(const f4*)p, u1 = *(const f4*)(p + 4);
      frag8 v;
      v[0]=(short)f2bf(u0[0]); v[1]=(short)f2bf(u0[1]); v[2]=(short)f2bf(u0[2]); v[3]=(short)f2bf(u0[3]);
      v[4]=(short)f2bf(u1[0]); v[5]=(short)f2bf(u1[1]); v[6]=(short)f2bf(u1[2]); v[7]=(short)f2bf(u1[3]);
      *(frag8*)&B1s[r][((c8 ^ (r & 7)) * 8)] = v;
      p = B3 + (size_t)r * HDIM + k0 + c8 * 8;
      u0 = *(const f4*)p; u1 = *(const f4*)(p + 4);
      v[0]=(short)f2bf(u0[0]); v[1]=(short)f2bf(u0[1]); v[2]=(short)f2bf(u0[2]); v[3]=(short)f2bf(u0[3]);
      v[4]=(short)f2bf(u1[0]); v[5]=(short)f2bf(u1[1]); v[6]=(short)f2bf(u1[2]); v[7]=(short)f2bf(u1[3]);
      *(frag8*)&B3s[r][((c8 ^ (r & 7)) * 8)] = v;
    }
    __syncthreads();
#pragma unroll
    for (int kk = 0; kk < 2; kk++) {
      frag8 a[4], b1[2], b3[2];
#pragma unroll
      for (int mi = 0; mi < 4; mi++) {
        int rr = wm + mi * 16 + lr;
        a[mi] = *(const frag8*)&As[rr][(((kk * 4 + lg) ^ (rr & 7)) * 8)];
      }
#pragma unroll
      for (int ni = 0; ni < 2; ni++) {
        int n = wn + ni * 16 + lr;
        int cc = ((kk * 4 + lg) ^ (n & 7)) * 8;
        b1[ni] = *(const frag8*)&B1s[n][cc];
        b3[ni] = *(const frag8*)&B3s[n][cc];
      }
#pragma unroll
      for (int mi = 0; mi < 4; mi++)
#pragma unroll
        for (int ni = 0; ni < 2; ni++) {
          acc1[mi][ni] = __builtin_amdgcn_mfma_f32_16x16x32_bf16(a[mi], b1[ni], acc1[mi][ni], 0, 0, 0);
          acc3[mi][ni] = __builtin_amdgcn_mfma_f32_16x16x32_bf16(a[mi], b3[ni], acc3[mi][ni], 0, 0, 0);
        }
    }
  }
#pragma unroll
  for (int mi = 0; mi < 4; mi++)
#pragma unroll
    for (int r = 0; r < 4; r++) {
      int grow = m0 + wm + mi * 16 + lg * 4 + r;
      if (grow < ce) {
        ushortT* hp = hbuf + (size_t)(oe + grow) * FDIM + f0 + wn;
#pragma unroll
        for (int ni = 0; ni < 2; ni++) {
          float z1 = acc1[mi][ni][r], z3 = acc3[mi][ni][r];
          float hg = z1 / (1.f + __expf(-z1)) * z3;
          hp[ni * 16 + lr] = f2bf(hg);
        }
      }
    }
}

// ---------------- MoE GEMM2: out += w * (hgate W2^T), scatter-atomic -------
__global__ __launch_bounds__(256) void k_moe_gemm2(
    const ushortT* __restrict__ hbuf, const float* __restrict__ W2,
    const int* __restrict__ ctrl, const int* __restrict__ slot_tok,
    const float* __restrict__ slot_w, float* __restrict__ outp) {
  int e = blockIdx.z, mt = blockIdx.y, nt = blockIdx.x;
  int ce = ctrl[e];
  int m0 = mt * 128;
  if (m0 >= ce) return;
  int oe = ctrl[8 + e];
  int h0 = nt * 128;
  const float* Bw = W2 + (size_t)e * HDIM * FDIM + (size_t)h0 * FDIM;
  __shared__ ushortT As[128][64];
  __shared__ ushortT Bs[128][64];
  int t = threadIdx.x;
  int l = t & 63, wid = t >> 6;
  int lr = l & 15, lg = l >> 4;
  int wm = (wid >> 1) * 64, wn = (wid & 1) * 64;
  v4f acc[4][4] = {};
  for (int k0 = 0; k0 < FDIM; k0 += 64) {
    __syncthreads();
#pragma unroll
    for (int c = 0; c < 4; c++) {
      int id = c * 256 + t;
      int r = id >> 3, c8 = id & 7;
      frag8 v = {};
      if (m0 + r < ce) v = *(const frag8*)(hbuf + (size_t)(oe + m0 + r) * FDIM + k0 + c8 * 8);
      *(frag8*)&As[r][((c8 ^ (r & 7)) * 8)] = v;
    }
#pragma unroll
    for (int c = 0; c < 4; c++) {
      int id = c * 256 + t;
      int r = id >> 3, c8 = id & 7;
      const float* p = Bw + (size_t)r * FDIM + k0 + c8 * 8;
      f4 u0 = *(const f4*)p, u1 = *(const f4*)(p + 4);
      frag8 v;
      v[0]=(short)f2bf(u0[0]); v[1]=(short)f2bf(u0[1]); v[2]=(short)f2bf(u0[2]); v[3]=(short)f2bf(u0[3]);
      v[4]=(short)f2bf(u1[0]); v[5]=(short)f2bf(u1[1]); v[6]=(short)f2bf(u1[2]); v[7]=(short)f2bf(u1[3]);
      *(frag8*)&Bs[r][((c8 ^ (r & 7)) * 8)] = v;
    }
    __syncthreads();
#pragma unroll
    for (int kk = 0; kk < 2; kk++) {
      frag8 a[4], b[4];
#pragma unroll
      for (int mi = 0; mi < 4; mi++) {
        int rr = wm + mi * 16 + lr;
        a[mi] = *(const frag8*)&As[rr][(((kk * 4 + lg) ^ (rr & 7)) * 8)];
      }
#pragma unroll
      for (int ni = 0; ni < 4; ni++) {
        int n = wn + ni * 16 + lr;
        b[ni] = *(const frag8*)&Bs[n][(((kk * 4 + lg) ^ (n & 7)) * 8)];
      }
#pragma unroll
      for (int mi = 0; mi < 4; mi++)
#pragma unroll
        for (int ni = 0; ni < 4; ni++)
          acc[mi][ni] = __builtin_amdgcn_mfma_f32_16x16x32_bf16(a[mi], b[ni], acc[mi][ni], 0, 0, 0);
    }
  }
#pragma unroll
  for (int mi = 0; mi < 4; mi++)
#pragma unroll
    for (int r = 0; r < 4; r++) {
      int grow = m0 + wm + mi * 16 + lg * 4 + r;
      if (grow < ce) {
        int slot = oe + grow;
        int tok = slot_tok[slot];
        float w = slot_w[slot];
        float* op = outp + (size_t)tok * HDIM + h0 + wn;
#pragma unroll
        for (int ni = 0; ni < 4; ni++)
          atomicAdd(op + ni * 16 + lr, w * acc[mi][ni][r]);
      }
    }
}

__global__ void k_lb(const int* ctrl, float* out) {
  if (threadIdx.x == 0) {
    const float* usage = (const float*)(ctrl + 24);
    float s = 0.f;
    for (int e = 0; e < 8; e++) { float u = usage[e] * (1.f / NTOK); s += u * u; }
    out[0] = 8.f * s;
  }
}

// ---------------- launch ----------------
extern "C" void kernel_launch(void* const* d_in, const int* in_sizes, int n_in,
                              void* d_out, int out_size, void* d_ws, size_t ws_size,
                              hipStream_t stream) {
  const float* x  = (const float*)d_in[0];
  const float* Wq = (const float*)d_in[1];
  const float* Wk = (const float*)d_in[2];
  const float* Wv = (const float*)d_in[3];
  const float* Wo = (const float*)d_in[4];
  const float* g1 = (const float*)d_in[5];
  const float* b1 = (const float*)d_in[6];
  const float* g2 = (const float*)d_in[7];
  const float* b2 = (const float*)d_in[8];
  const float* Wr = (const float*)d_in[9];
  const float* W1 = (const float*)d_in[10];
  const float* W2 = (const float*)d_in[11];
  const float* W3 = (const float*)d_in[12];
  float* outp = (float*)d_out;

  const size_t NHTOT = (size_t)NTOK * HDIM;  // 2M elements
  char* ws = (char*)d_ws;
  float* h1f   = (float*)ws;                 // 8 MB  (reused as attnf)
  float* qf    = h1f + NHTOT;                // 8 MB  (reused as x2)
  float* kf    = qf + NHTOT;                 // 8 MB  (reused as h2b)
  float* vf    = kf + NHTOT;                 // 8 MB
  float* attnf = h1f;
  float* x2    = qf;
  ushortT* h2b = (ushortT*)kf;
  ushortT* hbuf = (ushortT*)(vf + NHTOT);    // 4096 x 4096 bf16 = 32 MB
  int*   slot_tok = (int*)(hbuf + (size_t)4096 * FDIM);
  float* slot_w   = (float*)(slot_tok + 4096);
  int*   sel      = (int*)(slot_w + 4096);
  float* selw     = (float*)(sel + 2 * NTOK);
  int*   ctrl     = (int*)(selw + 2 * NTOK);

  k_zero<<<dim3(1), dim3(64), 0, stream>>>(ctrl);
  k_ln<<<dim3(NTOK), dim3(256), 0, stream>>>(x, g1, b1, h1f);

  // fused QKV (grid.z selects), then attention, then Wo(+residual, dual-write)
  k_gemm3<<<dim3(HDIM / 64, NTOK / 128, 3), dim3(256), 0, stream>>>(
      h1f, Wq, Wk, Wv, qf, kf, vf, nullptr, nullptr);

  k_attn_mfma<<<dim3(SEQ / 64, 32), dim3(256), 0, stream>>>(qf, kf, vf, attnf);

  k_gemm3<<<dim3(HDIM / 64, NTOK / 128, 1), dim3(256), 0, stream>>>(
      attnf, Wo, nullptr, nullptr, x2, nullptr, nullptr, x, outp);

  k_ln2_router<<<dim3(NTOK), dim3(256), 0, stream>>>(x2, g2, b2, Wr, h2b, sel, selw, ctrl);
  k_offsets<<<dim3(1), dim3(1), 0, stream>>>(ctrl);
  k_scatter<<<dim3(8), dim3(256), 0, stream>>>(sel, selw, ctrl, slot_tok, slot_w);

  k_moe_gemm1<<<dim3(FDIM / 64, 16, 8), dim3(256), 0, stream>>>(h2b, W1, W3, ctrl, slot_tok, hbuf);
  k_moe_gemm2<<<dim3(HDIM / 128, 16, 8), dim3(256), 0, stream>>>(hbuf, W2, ctrl, slot_tok, slot_w, outp);

  k_lb<<<dim3(1), dim3(64), 0, stream>>>(ctrl, outp + NHTOT);
}